// Round 9
// baseline (307.310 us; speedup 1.0000x reference)
//
#include <hip/hip_runtime.h>
#include <hip/hip_bf16.h>
#include <cstdint>
#include <cstddef>

#define F 768

typedef float f32x4 __attribute__((ext_vector_type(4)));
typedef short s16x8 __attribute__((ext_vector_type(8)));
typedef short s16x4 __attribute__((ext_vector_type(4)));

#define NEG_LOG2E (-1.4426950408889634f)

__device__ __forceinline__ float bf2f(unsigned short u) {
  union { unsigned int i; float f; } v; v.i = ((unsigned int)u) << 16; return v.f;
}
__device__ __forceinline__ unsigned short f2bf(float f) {
  union { float f; unsigned int i; } v; v.f = f;
  unsigned int r = v.i + 0x7FFF + ((v.i >> 16) & 1);  // RNE
  return (unsigned short)(r >> 16);
}

#if __has_builtin(__builtin_amdgcn_exp2f)
__device__ __forceinline__ float fexp2(float x) { return __builtin_amdgcn_exp2f(x); }
#else
__device__ __forceinline__ float fexp2(float x) { return exp2f(x); }
#endif
#if __has_builtin(__builtin_amdgcn_rcpf)
__device__ __forceinline__ float frcp(float x) { return __builtin_amdgcn_rcpf(x); }
#else
__device__ __forceinline__ float frcp(float x) { return 1.0f / x; }
#endif

__device__ __forceinline__ float ftanh(float x) {
  float t = fexp2(x * 2.8853900817779268f);
  float s = frcp(t + 1.0f);
  return fmaf(-2.0f, s, 1.0f);
}
__device__ __forceinline__ float fclamp60(float x) {
  return fminf(fmaxf(x, -60.0f), 60.0f);
}

__device__ __forceinline__ void gload16(const void* g, void* l) {
  __builtin_amdgcn_global_load_lds(
      (const __attribute__((address_space(1))) void*)g,
      (__attribute__((address_space(3))) void*)l, 16, 0, 0);
}

// ---------------- CSR build ----------------
__global__ void khist(const int* __restrict__ ei, int E, int* __restrict__ cnt) {
  int e = blockIdx.x * blockDim.x + threadIdx.x;
  if (e < E) atomicAdd(&cnt[ei[E + e]], 1);
}

__global__ void kscan(const int* __restrict__ cnt, int* __restrict__ offs, int n) {
  __shared__ int part[256];
  int t = threadIdx.x;
  const int per = n / 256;  // 8
  int local[8];
  int s = 0;
  for (int j = 0; j < per; ++j) { local[j] = cnt[t * per + j]; s += local[j]; }
  part[t] = s;
  __syncthreads();
  for (int d = 1; d < 256; d <<= 1) {
    int v = (t >= d) ? part[t - d] : 0;
    __syncthreads();
    part[t] += v;
    __syncthreads();
  }
  int run = (t == 0) ? 0 : part[t - 1];
  for (int j = 0; j < per; ++j) { offs[t * per + j] = run; run += local[j]; }
  if (t == 255) offs[n] = run;
}

__global__ void kscatter(const int* __restrict__ ei, const int* __restrict__ et, int E,
                         const int* __restrict__ offs, int* __restrict__ cur,
                         int* __restrict__ sorted) {
  int e = blockIdx.x * blockDim.x + threadIdx.x;
  if (e >= E) return;
  int dst = ei[E + e];
  int pos = offs[dst] + atomicAdd(&cur[dst], 1);
  sorted[pos] = ei[e] | (et[e] << 16);
}

// ---------------- merged prep: x->Acat, q->qbf, Wg/Wq -> Wgq/WgR/WqR ----------------
__global__ void kprep(const float* __restrict__ x, const float* __restrict__ q,
                      const float* __restrict__ Wg, const float* __restrict__ Wq,
                      int nx, int nq,
                      unsigned short* __restrict__ Acat, unsigned short* __restrict__ qbf,
                      unsigned short* __restrict__ Wgq, unsigned short* __restrict__ WgR,
                      unsigned short* __restrict__ WqR) {
  const int b = blockIdx.x, c = threadIdx.x * 4;
  const float* srow;
  unsigned short* drow;
  if (b < nx) {
    srow = x + (size_t)b * F; drow = Acat + (size_t)b * 3072;
  } else if (b < nx + nq) {
    srow = q + (size_t)(b - nx) * F; drow = qbf + (size_t)(b - nx) * F;
  } else {
    const int w = b - nx - nq;  // 0..3071
    if (w < 1536) {
      srow = (w < 768) ? Wg + (size_t)w * 1536 : Wq + (size_t)(w - 768) * 1536;
      drow = Wgq + (size_t)w * 768;
    } else if (w < 2304) {
      srow = Wg + (size_t)(w - 1536) * 1536 + 768;
      drow = WgR + (size_t)(w - 1536) * 768;
    } else {
      srow = Wq + (size_t)(w - 2304) * 1536 + 768;
      drow = WqR + (size_t)(w - 2304) * 768;
    }
  }
  float4 v = *(const float4*)(srow + c);
  s16x4 o;
  o[0] = (short)f2bf(v.x); o[1] = (short)f2bf(v.y);
  o[2] = (short)f2bf(v.z); o[3] = (short)f2bf(v.w);
  *(s16x4*)(drow + c) = o;
}

// transpose-convert: Wcat_l[n][part*768 + k] = Wpart[k][n], grid (12,12,8)
__global__ void ktrans(const float* __restrict__ Wr1, const float* __restrict__ Wl1,
                       const float* __restrict__ Wr2, const float* __restrict__ Wl2,
                       unsigned short* __restrict__ Wcat1, unsigned short* __restrict__ Wcat2) {
  __shared__ float tile[64][65];
  const int z = blockIdx.z, layer = z >> 2, part = z & 3;
  const float* src = (part == 0) ? (layer ? Wr2 : Wr1)
                                 : ((layer ? Wl2 : Wl1) + (size_t)(part - 1) * F * F);
  unsigned short* dst = (layer ? Wcat2 : Wcat1) + part * F;
  const int kt = blockIdx.x * 64, nt = blockIdx.y * 64;
  const int t = threadIdx.x, c = t & 63, r4 = t >> 6;
#pragma unroll
  for (int it = 0; it < 16; ++it) {
    int kk = r4 + it * 4;
    tile[kk][c] = src[(size_t)(kt + kk) * F + nt + c];
  }
  __syncthreads();
#pragma unroll
  for (int it = 0; it < 16; ++it) {
    int rr = r4 + it * 4;
    dst[(size_t)(nt + rr) * 3072 + kt + c] = f2bf(tile[c][rr]);
  }
}

// ---------------- per-(dst,relation) mean; 192 thr, ushort4/lane, unroll 4 ----------
__global__ void kagg(const int* __restrict__ offs, const int* __restrict__ sorted,
                     const unsigned short* __restrict__ hin,   // Acat left, ld 3072
                     unsigned short* __restrict__ dst) {       // Acat + 768
  const int i = blockIdx.x, t = threadIdx.x;
  const int col = t * 4;
  float a0[4] = {}, a1[4] = {}, a2[4] = {};
  int c0 = 0, c1 = 0, c2 = 0;
  const int beg = offs[i], end = offs[i + 1];
  int e = beg;
  for (; e + 3 < end; e += 4) {
    int pk[4];
#pragma unroll
    for (int u = 0; u < 4; ++u) pk[u] = sorted[e + u];
    s16x4 w[4];
#pragma unroll
    for (int u = 0; u < 4; ++u)
      w[u] = *(const s16x4*)(hin + (size_t)(pk[u] & 0xFFFF) * 3072 + col);
#pragma unroll
    for (int u = 0; u < 4; ++u) {
      int r = pk[u] >> 16;
      float v[4];
#pragma unroll
      for (int j = 0; j < 4; ++j) v[j] = bf2f((unsigned short)w[u][j]);
      if (r == 0)      { c0++; for (int j = 0; j < 4; ++j) a0[j] += v[j]; }
      else if (r == 1) { c1++; for (int j = 0; j < 4; ++j) a1[j] += v[j]; }
      else             { c2++; for (int j = 0; j < 4; ++j) a2[j] += v[j]; }
    }
  }
  for (; e < end; ++e) {
    int p0 = sorted[e];
    s16x4 w0 = *(const s16x4*)(hin + (size_t)(p0 & 0xFFFF) * 3072 + col);
    int r0 = p0 >> 16;
    float v0[4];
#pragma unroll
    for (int j = 0; j < 4; ++j) v0[j] = bf2f((unsigned short)w0[j]);
    if (r0 == 0)      { c0++; for (int j = 0; j < 4; ++j) a0[j] += v0[j]; }
    else if (r0 == 1) { c1++; for (int j = 0; j < 4; ++j) a1[j] += v0[j]; }
    else              { c2++; for (int j = 0; j < 4; ++j) a2[j] += v0[j]; }
  }
  const float i0 = frcp((float)(c0 > 0 ? c0 : 1));
  const float i1 = frcp((float)(c1 > 0 ? c1 : 1));
  const float i2 = frcp((float)(c2 > 0 ? c2 : 1));
  unsigned short* d = dst + (size_t)i * 3072 + col;
  s16x4 o;
#pragma unroll
  for (int j = 0; j < 4; ++j) o[j] = (short)f2bf(a0[j] * i0);
  *(s16x4*)d = o;
#pragma unroll
  for (int j = 0; j < 4; ++j) o[j] = (short)f2bf(a1[j] * i1);
  *(s16x4*)(d + F) = o;
#pragma unroll
  for (int j = 0; j < 4; ++j) o[j] = (short)f2bf(a2[j] * i2);
  *(s16x4*)(d + 2 * F) = o;
}

// ---------------- bf16 MFMA GEMM, 64x64 tile, BK=64, 512 thr / 8 waves ----------
// EPI: 2 relu(v+bias) -> bf16 C2 (hb)          (RGCN layer GEMM, K=3072)
//      3 gate-mix -> bf16 C2 (Acat) | 4 gate-mix -> f32 C (out)
//      6 qgE = exp2(clamp((v+bias)*-log2e)) -> f32 C
//      7 [hg|zh]: bn<768 -> fused qi (1-trans sigmoid via precomputed qgE),
//                 writes qib bf16 + tqb bf16; bn>=768 -> zh f32 -> C(zhb)
template <int EPI>
__launch_bounds__(512)
__global__ void kmm(const unsigned short* __restrict__ A, int lda,
                    const unsigned short* __restrict__ B, int ldb,
                    float* __restrict__ C, int ldc, int K,
                    const float* __restrict__ bias,          // EPI2: bb | EPI3/4: bq | EPI6: bg | EPI7: qgE
                    const float* __restrict__ auxf,          // EPI3/4: zhb | EPI7: raw q
                    const unsigned short* __restrict__ hbb,  // EPI3/4: hb bf16
                    unsigned short* __restrict__ C2, int ldc2,
                    unsigned short* __restrict__ tqb,        // EPI7: write | EPI3/4: read
                    int Lq) {
  __shared__ unsigned short Asb[2][64 * 64];
  __shared__ unsigned short Bsb[2][64 * 64];
  const int t = threadIdx.x;
  const int lane = t & 63, wid = t >> 6;     // 8 waves
  const int wr = wid >> 2, wc = wid & 3;     // 2 x 4
  const int bm = blockIdx.x * 64, bn = blockIdx.y * 64;

  const int srow = t >> 3, schunk = t & 7;
  const int kxor = ((schunk ^ (srow & 7)) << 3);
  const unsigned short* Ap = A + (size_t)(bm + srow) * lda + kxor;
  const unsigned short* Bp = B + (size_t)(bn + srow) * ldb + kxor;

  const int rA0 = wr * 32 + (lane & 15);
  const int rB0 = wc * 16 + (lane & 15);
  const int l7 = lane & 7, lq = lane >> 4;
  const int s8_0 = (((0 * 4 + lq) ^ l7) << 3);
  const int s8_1 = (((1 * 4 + lq) ^ l7) << 3);

  f32x4 acc[2] = {};

  auto stage = [&](int cb, int k0) {
    gload16(Ap + k0, &Asb[cb][t * 8]);
    gload16(Bp + k0, &Bsb[cb][t * 8]);
  };

  stage(0, 0);
  __syncthreads();
  int cur = 0;
  for (int k0 = 0; k0 < K; k0 += 64) {
    if (k0 + 64 < K) stage(cur ^ 1, k0 + 64);
    const unsigned short* As = Asb[cur];
    const unsigned short* Bs = Bsb[cur];
#pragma unroll
    for (int ks = 0; ks < 2; ++ks) {
      const int s8 = ks ? s8_1 : s8_0;
      s16x8 af[2], bf;
#pragma unroll
      for (int i = 0; i < 2; ++i)
        af[i] = *(const s16x8*)(As + (rA0 + i * 16) * 64 + s8);
      bf = *(const s16x8*)(Bs + rB0 * 64 + s8);
#pragma unroll
      for (int i = 0; i < 2; ++i)
        acc[i] = __builtin_amdgcn_mfma_f32_16x16x32_bf16(af[i], bf, acc[i], 0, 0, 0);
    }
    __syncthreads();
    cur ^= 1;
  }

  const int colw = bn + wc * 16 + (lane & 15);

  if (EPI == 7) {
    if (bn < 768) {
      // sig = 1/(1 + exp2(hg')·qgE_l): 1 trans per (element,l)
      float ea[2][4], qacc[2][4];
#pragma unroll
      for (int i = 0; i < 2; ++i)
#pragma unroll
        for (int j = 0; j < 4; ++j) {
          ea[i][j] = fexp2(fclamp60(acc[i][j] * NEG_LOG2E));
          qacc[i][j] = 0.0f;
        }
      const int b = bm >> 8;
      const float* qb = auxf + (size_t)b * Lq * F;   // raw q
      const float* qeb = bias + (size_t)b * Lq * F;  // qgE
#pragma unroll 4
      for (int l = 0; l < Lq; ++l) {
        const float qe = qeb[(size_t)l * F + colw];
        const float q0 = qb[(size_t)l * F + colw];
#pragma unroll
        for (int i = 0; i < 2; ++i)
#pragma unroll
          for (int j = 0; j < 4; ++j)
            qacc[i][j] = fmaf(frcp(fmaf(ea[i][j], qe, 1.0f)), q0, qacc[i][j]);
      }
#pragma unroll
      for (int i = 0; i < 2; ++i)
#pragma unroll
        for (int j = 0; j < 4; ++j) {
          const int row = bm + wr * 32 + i * 16 + (lane >> 4) * 4 + j;
          C2[(size_t)row * 768 + colw] = f2bf(qacc[i][j]);           // qib
          tqb[(size_t)row * 768 + colw] = f2bf(ftanh(qacc[i][j]));   // tq bf16
        }
    } else {
#pragma unroll
      for (int i = 0; i < 2; ++i)
#pragma unroll
        for (int j = 0; j < 4; ++j) {
          const int row = bm + wr * 32 + i * 16 + (lane >> 4) * 4 + j;
          C[(size_t)row * 768 + (colw - 768)] = acc[i][j];           // zhb
        }
    }
    return;
  }

#pragma unroll
  for (int i = 0; i < 2; ++i)
#pragma unroll
    for (int j = 0; j < 4; ++j) {
      const int row = bm + wr * 32 + i * 16 + (lane >> 4) * 4 + j;
      const int col = colw;
      float v = acc[i][j];
      if (EPI == 2) {
        v = fmaxf(v + bias[col], 0.0f);
        C2[(size_t)row * ldc2 + col] = f2bf(v);
      } else if (EPI == 3 || EPI == 4) {
        float zh = auxf[(size_t)row * 768 + col];
        float z = v + bias[col] + zh;
        float al = frcp(1.0f + fexp2(z * NEG_LOG2E));
        float tq = bf2f(tqb[(size_t)row * 768 + col]);
        float hv = bf2f(hbb[(size_t)row * 768 + col]);
        float o = al * tq + (1.0f - al) * hv;
        if (EPI == 3) C2[(size_t)row * ldc2 + col] = f2bf(o);
        else          C[(size_t)row * ldc + col] = o;
      } else if (EPI == 6) {
        C[(size_t)row * ldc + col] = fexp2(fclamp60((v + bias[col]) * NEG_LOG2E));
      }
    }
}

// ---------------- launch ----------------
extern "C" void kernel_launch(void* const* d_in, const int* in_sizes, int n_in,
                              void* d_out, int out_size, void* d_ws, size_t ws_size,
                              hipStream_t stream) {
  const float* x = (const float*)d_in[0];
  const int* ei = (const int*)d_in[1];
  const int* et = (const int*)d_in[2];
  const float* q = (const float*)d_in[3];
  const float* Wrel1 = (const float*)d_in[4];
  const float* Wroot1 = (const float*)d_in[5];
  const float* b1 = (const float*)d_in[6];
  const float* Wrel2 = (const float*)d_in[7];
  const float* Wroot2 = (const float*)d_in[8];
  const float* b2 = (const float*)d_in[9];
  const float* Wg = (const float*)d_in[10];
  const float* bg = (const float*)d_in[11];
  const float* Wq = (const float*)d_in[12];
  const float* bq = (const float*)d_in[13];

  const int BNn = in_sizes[0] / F;       // 2048
  const int E = in_sizes[1] / 2;         // 65536
  const int L = 64;
  const int Bq = in_sizes[3] / (L * F);  // 8
  const int ML = Bq * L;                 // 512
  float* out = (float*)d_out;

  char* p = (char*)d_ws;
  auto alloc = [&](size_t bytes) {
    void* r = (void*)p;
    p += (bytes + 255) & ~(size_t)255;
    return r;
  };
  int* cntcur = (int*)alloc((size_t)2 * BNn * 4);  // cnt | cur, one memset
  int* cnt = cntcur;
  int* cur = cntcur + BNn;
  int* offs = (int*)alloc((size_t)(BNn + 1) * 4);
  int* sorted = (int*)alloc((size_t)E * 4);
  unsigned short* Acat = (unsigned short*)alloc((size_t)BNn * 3072 * 2);
  unsigned short* Wcat1 = (unsigned short*)alloc((size_t)F * 3072 * 2);
  unsigned short* Wcat2 = (unsigned short*)alloc((size_t)F * 3072 * 2);
  unsigned short* Wgq = (unsigned short*)alloc((size_t)1536 * F * 2);
  unsigned short* WgR = (unsigned short*)alloc((size_t)F * F * 2);
  unsigned short* WqR = (unsigned short*)alloc((size_t)F * F * 2);
  unsigned short* qbf = (unsigned short*)alloc((size_t)ML * F * 2);
  float* qgE = (float*)alloc((size_t)ML * F * 4);
  unsigned short* hb = (unsigned short*)alloc((size_t)BNn * F * 2);
  float* zhb = (float*)alloc((size_t)BNn * F * 4);
  unsigned short* tqb = (unsigned short*)alloc((size_t)BNn * F * 2);
  unsigned short* qib = (unsigned short*)alloc((size_t)BNn * F * 2);

  hipMemsetAsync(cntcur, 0, (size_t)2 * BNn * 4, stream);
  khist<<<(E + 255) / 256, 256, 0, stream>>>(ei, E, cnt);
  kscan<<<1, 256, 0, stream>>>(cnt, offs, BNn);
  kscatter<<<(E + 255) / 256, 256, 0, stream>>>(ei, et, E, offs, cur, sorted);

  kprep<<<BNn + ML + 3072, 192, 0, stream>>>(x, q, Wg, Wq, BNn, ML,
                                             Acat, qbf, Wgq, WgR, WqR);
  ktrans<<<dim3(12, 12, 8), 256, 0, stream>>>(Wroot1, Wrel1, Wroot2, Wrel2, Wcat1, Wcat2);

  // qgE = exp2(clamp(-(q @ Wg[:,F:].T + bg)·log2e))  (once, reused by both gates)
  kmm<6><<<dim3(ML / 64, F / 64), 512, 0, stream>>>(
      qbf, F, WgR, F, qgE, F, F, bg, nullptr, nullptr, nullptr, 0, nullptr, L);

  for (int layer = 0; layer < 2; ++layer) {
    const unsigned short* Wcat = layer ? Wcat2 : Wcat1;
    const float* bb = layer ? b2 : b1;

    // Acat right = per-relation means of Acat left
    kagg<<<BNn, 192, 0, stream>>>(offs, sorted, Acat, Acat + F);

    // hb = bf16(relu(Acat @ Wcat.T + bias))  -- direct K=3072, fused epilogue
    kmm<2><<<dim3(BNn / 64, F / 64), 512, 0, stream>>>(
        Acat, 3072, Wcat, 3072, nullptr, 0, 3072, bb, nullptr, nullptr, hb, F, nullptr, L);

    // [hg | zh] = hb @ [WgL | WqL].T ; fused qi (1-trans sigmoid) on hg half
    kmm<7><<<dim3(BNn / 64, 1536 / 64), 512, 0, stream>>>(
        hb, F, Wgq, F, zhb, F, F, qgE, q, nullptr, qib, F, tqb, L);

    // z = zh + qi @ WqR.T + bq ; out = sig(z)*tq + (1-sig(z))*hb
    if (layer == 0) {
      kmm<3><<<dim3(BNn / 64, F / 64), 512, 0, stream>>>(
          qib, F, WqR, F, nullptr, 0, F, bq, zhb, hb, Acat, 3072, tqb, L);
    } else {
      kmm<4><<<dim3(BNn / 64, F / 64), 512, 0, stream>>>(
          qib, F, WqR, F, out, F, F, bq, zhb, hb, nullptr, 0, tqb, L);
    }
  }
}